// Round 3
// baseline (374.662 us; speedup 1.0000x reference)
//
#include <hip/hip_runtime.h>
#include <hip/hip_bf16.h>
#include <math.h>

typedef __hip_bfloat16 bf16;
typedef __attribute__((ext_vector_type(8))) short bf16x8;
typedef __attribute__((ext_vector_type(4))) float f32x4;

__device__ __forceinline__ unsigned short f2bf_rne(float f) {
  unsigned u = __float_as_uint(f);
  u += 0x7fffu + ((u >> 16) & 1u);
  return (unsigned short)(u >> 16);
}
__device__ __forceinline__ float bf2f(unsigned short s) {
  return __uint_as_float(((unsigned)s) << 16);
}

// fast tanh-form GELU: max |diff| vs exact erf-GELU ~1e-3
__device__ __forceinline__ float gelu_fast(float v) {
  float u = v * (0.7978845608f + 0.0356774081f * v * v);
  float t = __builtin_amdgcn_exp2f(u * 2.8853900818f);
  float r = __builtin_amdgcn_rcpf(t + 1.0f);
  return v - v * r;
}

#define GLOBAL_AS __attribute__((address_space(1)))
#define LDS_AS __attribute__((address_space(3)))
__device__ __forceinline__ void gl2lds16(const void* g, void* l) {
  __builtin_amdgcn_global_load_lds((const GLOBAL_AS void*)g, (LDS_AS void*)l, 16, 0, 0);
}

// ---------------- LayerNorm: x f32 [rows][1024] -> h bf16 ----------------
__global__ __launch_bounds__(256) void ln_kernel(const float* __restrict__ x,
                                                 const float* __restrict__ g,
                                                 const float* __restrict__ b,
                                                 bf16* __restrict__ h) {
  int row = blockIdx.x, t = threadIdx.x;
  const float4 xv = ((const float4*)(x + (size_t)row * 1024))[t];
  float s = xv.x + xv.y + xv.z + xv.w;
  float sq = xv.x * xv.x + xv.y * xv.y + xv.z * xv.z + xv.w * xv.w;
  #pragma unroll
  for (int m = 1; m < 64; m <<= 1) { s += __shfl_xor(s, m); sq += __shfl_xor(sq, m); }
  __shared__ float ps[4], pq[4];
  if ((t & 63) == 0) { ps[t >> 6] = s; pq[t >> 6] = sq; }
  __syncthreads();
  s = ps[0] + ps[1] + ps[2] + ps[3];
  sq = pq[0] + pq[1] + pq[2] + pq[3];
  float mean = s * (1.0f / 1024.0f);
  float var = sq * (1.0f / 1024.0f) - mean * mean;
  float rs = rsqrtf(var + 1e-3f);
  float4 gv = ((const float4*)g)[t];
  float4 bv = ((const float4*)b)[t];
  ushort4 o;
  o.x = f2bf_rne((xv.x - mean) * rs * gv.x + bv.x);
  o.y = f2bf_rne((xv.y - mean) * rs * gv.y + bv.y);
  o.z = f2bf_rne((xv.z - mean) * rs * gv.z + bv.z);
  o.w = f2bf_rne((xv.w - mean) * rs * gv.w + bv.w);
  ((ushort4*)(h + (size_t)row * 1024))[t] = o;
}

// ------------- merged transpose + f32->bf16 for all 5 weights -------------
__device__ __forceinline__ void tr_tile(const float* __restrict__ W, bf16* __restrict__ WT,
                                        int R, int Cc, int bx, int by, int t) {
  __shared__ float tile[32][33];
  int tx = t & 31, ty = t >> 5;
  #pragma unroll
  for (int k = 0; k < 4; k++) {
    int rr = ty + k * 8;
    tile[rr][tx] = W[(size_t)(by + rr) * Cc + bx + tx];
  }
  __syncthreads();
  unsigned short* out = reinterpret_cast<unsigned short*>(WT);
  #pragma unroll
  for (int k = 0; k < 4; k++) {
    int rr = ty + k * 8;
    out[(size_t)(bx + rr) * R + by + tx] = f2bf_rne(tile[tx][rr]);
  }
}

__global__ __launch_bounds__(256) void transpose_all(const float* __restrict__ Wq,
                                                     const float* __restrict__ Wk,
                                                     const float* __restrict__ Wv,
                                                     const float* __restrict__ W1,
                                                     const float* __restrict__ W2,
                                                     bf16* __restrict__ WqkT,
                                                     bf16* __restrict__ W1T,
                                                     bf16* __restrict__ W2T) {
  int id = blockIdx.x, t = threadIdx.x;
  if (id < 3072) {
    int sect = id >> 10, r = id & 1023;
    const float* W = sect == 0 ? Wq : (sect == 1 ? Wk : Wv);
    bf16* WT = WqkT + (size_t)sect * 1048576;
    tr_tile(W, WT, 1024, 1024, (r & 31) * 32, (r >> 5) * 32, t);
  } else if (id < 7168) {
    int r = id - 3072;
    tr_tile(W1, W1T, 1024, 4096, (r & 127) * 32, (r >> 7) * 32, t);
  } else {
    int r = id - 7168;
    tr_tile(W2, W2T, 4096, 1024, (r & 31) * 32, (r >> 5) * 32, t);
  }
}

// ============ 256x256 8-phase GEMM mainloop (T2+T3+T4+T5) ============
// BK=64, 512 threads (8 waves, 2Mx4N), per-wave 128x64 out, LDS 128KB:
// [A0 32K | B0 32K | A1 32K | B1 32K], tile kt -> buffer kt&1.
// Per iteration (2 K-tiles, 8 phases): phase = {ds_read subtile, stage 1
// half-tile, s_barrier, lgkmcnt(0), setprio(1) 16xMFMA setprio(0), barrier}.
// Counted vmcnt(4) ONLY at phases 4 and 8: tile t+1 landed, tile t+2's B
// stays in flight across the barrier. Stage slots: p1,p2=(t+1).A->nxt;
// p3,p4=(t+2).B->cur; p5,p6=(t+2).A->cur; p7,p8=(t+3).B->nxt. Each target
// half was last ds_read >=1 barrier earlier (freed).
// lda = row stride of A/BT (elements); nk = K-extent to process (multiple
// of 128). Caller pre-offsets A/BT for split-K slices.
__device__ __forceinline__ void mainloop_256(const bf16* __restrict__ A,
                                             const bf16* __restrict__ BT,
                                             int lda, int nk, int m0, int n0,
                                             char* ldsb, int t,
                                             f32x4 (&acc)[8][4]) {
  const int lane = t & 63, wave = t >> 6;
  const int l = lane & 15, quad = lane >> 4;
  const int wm = (wave >> 2) * 128, wn = (wave & 3) * 64;
  const int srow = wave * 8 + (lane >> 3);          // row within 64-row round
  const int scol = ((lane & 7) ^ (lane >> 3)) * 8;  // pre-swizzled global col
  const int grp0 = (quad ^ (l & 7)) * 16;           // swizzled 16B group, k-slice 0
  const int grp1 = ((4 + quad) ^ (l & 7)) * 16;     // k-slice 1

  bf16x8 a[4][2], b01[2][2], b23[2][2];

  auto stA = [&](int buf, int half, int kt) {
    const bf16* s = A + (size_t)(m0 + half * 128 + srow) * lda + kt * 64 + scol;
    char* d = ldsb + buf * 65536 + half * 16384 + wave * 1024;
    gl2lds16(s, d);
    gl2lds16(s + (size_t)64 * lda, d + 8192);
  };
  auto stB = [&](int buf, int half, int kt) {
    const bf16* s = BT + (size_t)(n0 + half * 128 + srow) * lda + kt * 64 + scol;
    char* d = ldsb + buf * 65536 + 32768 + half * 16384 + wave * 1024;
    gl2lds16(s, d);
    gl2lds16(s + (size_t)64 * lda, d + 8192);
  };
  auto rdA = [&](int buf, int mh) {
    const char* base = ldsb + buf * 65536 + (wm + mh * 64 + l) * 128;
    #pragma unroll
    for (int ii = 0; ii < 4; ii++) {
      a[ii][0] = *(const bf16x8*)(base + ii * 2048 + grp0);
      a[ii][1] = *(const bf16x8*)(base + ii * 2048 + grp1);
    }
  };
  auto rdB = [&](int buf, int nh, bf16x8 (&bb)[2][2]) {
    const char* base = ldsb + buf * 65536 + 32768 + (wn + nh * 32 + l) * 128;
    #pragma unroll
    for (int jj = 0; jj < 2; jj++) {
      bb[jj][0] = *(const bf16x8*)(base + jj * 2048 + grp0);
      bb[jj][1] = *(const bf16x8*)(base + jj * 2048 + grp1);
    }
  };
  auto mm4 = [&](int mi, bf16x8 (&bb)[2][2], int nj) {
    #pragma unroll
    for (int ii = 0; ii < 4; ii++)
      #pragma unroll
      for (int jj = 0; jj < 2; jj++) {
        acc[mi + ii][nj + jj] = __builtin_amdgcn_mfma_f32_16x16x32_bf16(
            a[ii][0], bb[jj][0], acc[mi + ii][nj + jj], 0, 0, 0);
        acc[mi + ii][nj + jj] = __builtin_amdgcn_mfma_f32_16x16x32_bf16(
            a[ii][1], bb[jj][1], acc[mi + ii][nj + jj], 0, 0, 0);
      }
  };

#define BARX() __builtin_amdgcn_s_barrier()
#define LGKM0() do { asm volatile("s_waitcnt lgkmcnt(0)" ::: "memory"); \
                     __builtin_amdgcn_sched_barrier(0); } while (0)
#define HALF4(BC, DOA, SAB, SAK, DOB, SBB, SBK, VMN)                      \
  do {                                                                    \
    rdA(BC, 0); rdB(BC, 0, b01);                                          \
    if (DOA) stA(SAB, 0, SAK);                                            \
    BARX(); LGKM0();                                                      \
    __builtin_amdgcn_s_setprio(1); mm4(0, b01, 0);                        \
    __builtin_amdgcn_s_setprio(0); BARX();                                \
    rdB(BC, 1, b23);                                                      \
    if (DOA) stA(SAB, 1, SAK);                                            \
    BARX(); LGKM0();                                                      \
    __builtin_amdgcn_s_setprio(1); mm4(0, b23, 2);                        \
    __builtin_amdgcn_s_setprio(0); BARX();                                \
    rdA(BC, 1);                                                           \
    if (DOB) stB(SBB, 0, SBK);                                            \
    BARX(); LGKM0();                                                      \
    __builtin_amdgcn_s_setprio(1); mm4(4, b01, 0);                        \
    __builtin_amdgcn_s_setprio(0); BARX();                                \
    if (DOB) stB(SBB, 1, SBK);                                            \
    BARX();                                                               \
    __builtin_amdgcn_s_setprio(1); mm4(4, b23, 2);                        \
    __builtin_amdgcn_s_setprio(0);                                        \
    asm volatile("s_waitcnt vmcnt(" VMN ")" ::: "memory");                \
    BARX();                                                               \
  } while (0)

  const int nt = nk >> 6;
  // prologue: tile0 (8 loads) + tile1.B (4 loads); vmcnt(4) -> tile0 landed
  stA(0, 0, 0); stA(0, 1, 0);
  stB(0, 0, 0); stB(0, 1, 0);
  stB(1, 0, 1); stB(1, 1, 1);
  asm volatile("s_waitcnt vmcnt(4)" ::: "memory");
  BARX();
  int tt = 0;
  for (; tt + 2 < nt; tt += 2) {
    HALF4(0, 1, 1, tt + 1, 1, 0, tt + 2, "4");
    HALF4(1, 1, 0, tt + 2, 1, 1, tt + 3, "4");
  }
  // tail: tt = nt-2; stage only (nt-1).A, drain fully before last tile
  HALF4(0, 1, 1, tt + 1, 0, 0, 0, "0");
  HALF4(1, 0, 0, 0, 0, 0, 0, "0");
#undef HALF4
#undef LGKM0
#undef BARX
}

// ---------------- FFN1: act bf16 = gelu(h @ W1 + b1), N=4096 K=1024 ---------
__global__ __launch_bounds__(512, 2) void gemm_ffn1(const bf16* __restrict__ A,
                                                    const bf16* __restrict__ BT,
                                                    const float* __restrict__ bias,
                                                    bf16* __restrict__ out,
                                                    int N, int K) {
  extern __shared__ char lds[];
  int t = threadIdx.x;
  int n0 = blockIdx.x * 256, m0 = blockIdx.y * 256;
  f32x4 acc[8][4];
  #pragma unroll
  for (int i = 0; i < 8; i++)
    #pragma unroll
    for (int j = 0; j < 4; j++) acc[i][j] = (f32x4){0.f, 0.f, 0.f, 0.f};
  mainloop_256(A, BT, K, K, m0, n0, lds, t, acc);

  int lane = t & 63, wave = t >> 6;
  int l = lane & 15, quad = lane >> 4;
  int wm = (wave >> 2) * 128, wn = (wave & 3) * 64;
  int r4 = quad * 4;
  unsigned short* os = reinterpret_cast<unsigned short*>(out);
  #pragma unroll
  for (int i = 0; i < 8; i++)
    #pragma unroll
    for (int j = 0; j < 4; j++) {
      int col = n0 + wn + j * 16 + l;
      float bval = bias[col];
      #pragma unroll
      for (int r = 0; r < 4; r++) {
        int row = m0 + wm + i * 16 + r4 + r;
        os[(size_t)row * N + col] = f2bf_rne(gelu_fast(acc[i][j][r] + bval));
      }
    }
}

// ------- FFN2 split-K (8-phase): partial[z] bf16 = act[:,z] @ W2T[:,z] ------
// M=4096 N=1024 K=4096, z in 0..3 each K=1024; grid (4,16,4)=256 blocks
// = 1 block/CU (128KB LDS). lda=4096, per-slice nk=1024 (nt=16, same as FFN1).
__global__ __launch_bounds__(512, 2) void gemm_ffn2(const bf16* __restrict__ A,
                                                    const bf16* __restrict__ BT,
                                                    unsigned short* __restrict__ p0,
                                                    unsigned short* __restrict__ p1,
                                                    unsigned short* __restrict__ p2,
                                                    unsigned short* __restrict__ p3) {
  extern __shared__ char lds[];
  int t = threadIdx.x;
  int n0 = blockIdx.x * 256, m0 = blockIdx.y * 256;
  int z = blockIdx.z;
  f32x4 acc[8][4];
  #pragma unroll
  for (int i = 0; i < 8; i++)
    #pragma unroll
    for (int j = 0; j < 4; j++) acc[i][j] = (f32x4){0.f, 0.f, 0.f, 0.f};
  mainloop_256(A + z * 1024, BT + z * 1024, 4096, 1024, m0, n0, lds, t, acc);

  unsigned short* p = z == 0 ? p0 : (z == 1 ? p1 : (z == 2 ? p2 : p3));
  int lane = t & 63, wave = t >> 6;
  int l = lane & 15, quad = lane >> 4;
  int wm = (wave >> 2) * 128, wn = (wave & 3) * 64;
  int r4 = quad * 4;
  #pragma unroll
  for (int i = 0; i < 8; i++)
    #pragma unroll
    for (int j = 0; j < 4; j++) {
      int col = n0 + wn + j * 16 + l;
      #pragma unroll
      for (int r = 0; r < 4; r++) {
        int row = m0 + wm + i * 16 + r4 + r;
        p[(size_t)row * 1024 + col] = f2bf_rne(acc[i][j][r]);
      }
    }
}

// -------- FFN2 reduce: out f32 = p0 + p1 + p2 + p3 + bias + x1 --------
__global__ __launch_bounds__(256) void reduce_ffn2(const unsigned short* __restrict__ p0,
                                                   const unsigned short* __restrict__ p1,
                                                   const unsigned short* __restrict__ p2,
                                                   const unsigned short* __restrict__ p3,
                                                   const float* __restrict__ x1,
                                                   const float* __restrict__ bias,
                                                   float* __restrict__ out) {
  int row = blockIdx.x, t = threadIdx.x;
  size_t base = (size_t)row * 1024;
  ushort4 a = ((const ushort4*)(p0 + base))[t];
  ushort4 b = ((const ushort4*)(p1 + base))[t];
  ushort4 c = ((const ushort4*)(p2 + base))[t];
  ushort4 d = ((const ushort4*)(p3 + base))[t];
  float4 xv = ((const float4*)(x1 + base))[t];
  float4 bv = ((const float4*)bias)[t];
  float4 o;
  o.x = (bf2f(a.x) + bf2f(b.x)) + (bf2f(c.x) + bf2f(d.x)) + xv.x + bv.x;
  o.y = (bf2f(a.y) + bf2f(b.y)) + (bf2f(c.y) + bf2f(d.y)) + xv.y + bv.y;
  o.z = (bf2f(a.z) + bf2f(b.z)) + (bf2f(c.z) + bf2f(d.z)) + xv.z + bv.z;
  o.w = (bf2f(a.w) + bf2f(b.w)) + (bf2f(c.w) + bf2f(d.w)) + xv.w + bv.w;
  ((float4*)(out + base))[t] = o;
}

// ------------- fused QKV GEMM: N=3072 (q|k|v); v written transposed ----------
__global__ __launch_bounds__(512, 2) void gemm_qkv(const bf16* __restrict__ A,
                                                   const bf16* __restrict__ BT,
                                                   const float* __restrict__ bq,
                                                   const float* __restrict__ bk,
                                                   const float* __restrict__ bv,
                                                   bf16* __restrict__ qb,
                                                   bf16* __restrict__ kb,
                                                   bf16* __restrict__ vt,
                                                   int K) {
  extern __shared__ char lds[];
  int t = threadIdx.x;
  int n0 = blockIdx.x * 256, m0 = blockIdx.y * 256;
  f32x4 acc[8][4];
  #pragma unroll
  for (int i = 0; i < 8; i++)
    #pragma unroll
    for (int j = 0; j < 4; j++) acc[i][j] = (f32x4){0.f, 0.f, 0.f, 0.f};
  mainloop_256(A, BT, K, K, m0, n0, lds, t, acc);

  int lane = t & 63, wave = t >> 6;
  int l = lane & 15, quad = lane >> 4;
  int wm = (wave >> 2) * 128, wn = (wave & 3) * 64;
  int sect = n0 >> 10;  // 0=q 1=k 2=v (BN=256 divides 1024 sections)
  const float* bias = sect == 0 ? bq : (sect == 1 ? bk : bv);
  int r4 = quad * 4;
  #pragma unroll
  for (int i = 0; i < 8; i++)
    #pragma unroll
    for (int j = 0; j < 4; j++) {
      int col = n0 + wn + j * 16 + l;
      int c1 = col & 1023;
      float bval = bias[c1];
      int row0 = m0 + wm + i * 16 + r4;
      if (sect < 2) {
        bf16* o = sect == 0 ? qb : kb;
        unsigned short* os = reinterpret_cast<unsigned short*>(o);
        #pragma unroll
        for (int r = 0; r < 4; r++)
          os[(size_t)(row0 + r) * 1024 + c1] = f2bf_rne(acc[i][j][r] + bval);
      } else {
        int hh = c1 >> 6, d = c1 & 63;
        int b = row0 >> 11, t0 = row0 & 2047;
        ushort4 pk;
        pk.x = f2bf_rne(acc[i][j][0] + bval);
        pk.y = f2bf_rne(acc[i][j][1] + bval);
        pk.z = f2bf_rne(acc[i][j][2] + bval);
        pk.w = f2bf_rne(acc[i][j][3] + bval);
        *(ushort4*)((unsigned short*)vt + (size_t)((b * 16 + hh) * 64 + d) * 2048 + t0) = pk;
      }
    }
}

// ---------------- MFMA flash attention v5 ----------------
// 512 threads = 8 fully-independent waves; waves 0-3 run i-tile y, waves
// 4-7 run i-tile 31-y CONCURRENTLY (33 j-units/block, balanced). K, V, Q
// fragments are loaded DIRECT from global (fragment layout = 16B-contiguous
// rows; L1/L2-served) -> no KV staging, no barriers, no cross-wave coupling.
// Only LDS use: per-wave private P quad-exchange [16][68] (ds_write ->
// lgkmcnt(0) -> ds_read, own-wave only). 2 blocks/CU = 4 waves/SIMD.
__global__ __launch_bounds__(512, 4) void attn_mfma(const bf16* __restrict__ qb,
                                                    const bf16* __restrict__ kb,
                                                    const bf16* __restrict__ vt,
                                                    const float* __restrict__ x,
                                                    float* __restrict__ x1) {
  __shared__ bf16 P[8][16][68];  // per-wave private quad-exchange buffer
  int t = threadIdx.x;
  int bh = blockIdx.x;
  int b = bh >> 4, h = bh & 15;
  size_t qk_base = (size_t)b * 2048 * 1024 + (size_t)h * 64;
  size_t vt_base = (size_t)bh * 64 * 2048;
  int lane = t & 63, wave = t >> 6;
  int l = lane & 15, quad = lane >> 4;
  const float cs = 0.125f * 1.44269504088896f;  // scale * log2(e)
  int y = blockIdx.y;
  int half = wave >> 2, w4 = wave & 3;
  int it = half ? 31 - y : y;
  int i0 = it * 64;
  int iblk = i0 + w4 * 16;
  int njt = it + 1;

  // Q fragment (role-swapped: scores[i,j] = k_i . q_j, so "Q" comes from kb)
  const bf16* qrow = kb + qk_base + (size_t)(iblk + l) * 1024;
  bf16x8 qf0 = *(const bf16x8*)(qrow + quad * 8);
  bf16x8 qf1 = *(const bf16x8*)(qrow + 32 + quad * 8);

  float lsum = 0.f;
  f32x4 Oacc[4];
  #pragma unroll
  for (int dt = 0; dt < 4; dt++) Oacc[dt] = (f32x4){0.f, 0.f, 0.f, 0.f};

  bf16 (*Pw)[68] = P[wave];

  for (int jt = 0; jt < njt; jt++) {
    int j0v = jt * 64;
    const bf16* Kb = qb + qk_base + (size_t)j0v * 1024;
    // S^T per nt: A = K rows (m=j) direct from global, B = Q frag (n=i)
    #pragma unroll
    for (int nt = 0; nt < 4; nt++) {
      int jb = j0v + nt * 16;
      uint2 pk;
      if (jb > iblk + 15) {  // fully masked
        pk.x = 0u; pk.y = 0u;
      } else {
        const bf16* kr = Kb + (size_t)(nt * 16 + l) * 1024;
        bf16x8 kf0 = *(const bf16x8*)(kr + quad * 8);
        bf16x8 kf1 = *(const bf16x8*)(kr + 32 + quad * 8);
        f32x4 sv = (f32x4){0.f, 0.f, 0.f, 0.f};
        sv = __builtin_amdgcn_mfma_f32_16x16x32_bf16(kf0, qf0, sv, 0, 0, 0);
        sv = __builtin_amdgcn_mfma_f32_16x16x32_bf16(kf1, qf1, sv, 0, 0, 0);
        float p0, p1, p2, p3;
        if (jb + 15 <= iblk) {  // fully unmasked
          p0 = __builtin_amdgcn_exp2f(sv[0] * cs);
          p1 = __builtin_amdgcn_exp2f(sv[1] * cs);
          p2 = __builtin_amdgcn_exp2f(sv[2] * cs);
          p3 = __builtin_amdgcn_exp2f(sv[3] * cs);
        } else {                // diagonal straddle
          int i_ = iblk + l, jbase = jb + quad * 4;
          p0 = (jbase + 0 > i_) ? 0.f : __builtin_amdgcn_exp2f(sv[0] * cs);
          p1 = (jbase + 1 > i_) ? 0.f : __builtin_amdgcn_exp2f(sv[1] * cs);
          p2 = (jbase + 2 > i_) ? 0.f : __builtin_amdgcn_exp2f(sv[2] * cs);
          p3 = (jbase + 3 > i_) ? 0.f : __builtin_amdgcn_exp2f(sv[3] * cs);
        }
        lsum += (p0 + p1) + (p2 + p3);
        union { __hip_bfloat162 h2; unsigned u; } c0u, c1u;
        c0u.h2 = __float22bfloat162_rn(make_float2(p0, p1));
        c1u.h2 = __float22bfloat162_rn(make_float2(p2, p3));
        pk.x = c0u.u; pk.y = c1u.u;
      }
      *(uint2*)&Pw[l][nt * 16 + quad * 4] = pk;
    }
    asm volatile("s_waitcnt lgkmcnt(0)" ::: "memory");  // own-wave P only

    // PV: A = P rows (m=i) from LDS, B = V rows (n=d) direct from global
    bf16x8 ap0 = *(const bf16x8*)&Pw[l][quad * 8];
    const bf16* Vb = vt + vt_base + j0v;
    if ((jt < it) || (w4 >= 2)) {  // j in [32,64) has live P
      bf16x8 ap1 = *(const bf16x8*)&Pw[l][32 + quad * 8];
      #pragma unroll
      for (int dt = 0; dt < 4; dt++) {
        const bf16* vr = Vb + (size_t)(dt * 16 + l) * 2048;
        bf16x8 bv0 = *(const bf16x8*)(vr + quad * 8);
        bf16x8 bv1 = *(const bf16x8*)(vr + 32 + quad * 8);
        Oacc[dt] = __builtin_amdgcn_mfma_f32_16x16x32_bf16(ap0, bv0, Oacc[dt], 0, 0, 0);
        Oacc[dt] = __builtin_amdgcn_mfma_f32_16x16x32_bf16(ap1, bv1, Oacc[dt], 0, 0, 0);
      }
    } else {
      #pragma unroll
      for (int dt = 0; dt < 4; dt++) {
        const bf16* vr = Vb + (size_t)(dt * 16 + l) * 2048;
        bf16x8 bv0 = *(const bf16x8*)(vr + quad * 8);
        Oacc[dt] = __builtin_amdgcn_mfma_f32_16x16x32_bf16(ap0, bv0, Oacc[dt], 0, 0, 0);
      }
    }
  }

  // denominator: sum over quads (each lane's lsum is i=l partial)
  lsum += __shfl_xor(lsum, 16);
  lsum += __shfl_xor(lsum, 32);
  #pragma unroll
  for (int r = 0; r < 4; r++) {
    float lv = __shfl(lsum, quad * 4 + r);
    float inv = 1.0f / lv;
    int row = iblk + quad * 4 + r;
    size_t gi = qk_base + (size_t)row * 1024;
    #pragma unroll
    for (int dt = 0; dt < 4; dt++) {
      int d = dt * 16 + l;
      x1[gi + d] = x[gi + d] + Oacc[dt][r] * inv;
    }
  }
}

extern "C" void kernel_launch(void* const* d_in, const int* in_sizes, int n_in,
                              void* d_out, int out_size, void* d_ws, size_t ws_size,
                              hipStream_t stream) {
  const float* x    = (const float*)d_in[0];
  const float* ln1g = (const float*)d_in[1];
  const float* ln1b = (const float*)d_in[2];
  const float* Wq   = (const float*)d_in[3];
  const float* bq   = (const float*)d_in[4];
  const float* Wk   = (const float*)d_in[5];
  const float* bk   = (const float*)d_in[6];
  const float* Wv   = (const float*)d_in[7];
  const float* bv   = (const float*)d_in[8];
  const float* ln2g = (const float*)d_in[9];
  const float* ln2b = (const float*)d_in[10];
  const float* W1   = (const float*)d_in[11];
  const float* b1   = (const float*)d_in[12];
  const float* W2   = (const float*)d_in[13];
  const float* b2   = (const float*)d_in[14];

  char* ws = (char*)d_ws;
  float* x1  = (float*)(ws + 0);            // 16 MB f32 [4096][1024]
  bf16* h    = (bf16*)(ws + 16777216);      //  8 MB bf16 [4096][1024]  (reused: FFN2 partial 3)
  bf16* WqkT = (bf16*)(ws + 25165824);      //  6 MB bf16 [3072][1024] (q|k|v)
  bf16* W1T  = (bf16*)(ws + 31457280);      //  8 MB [4096][1024]
  bf16* W2T  = (bf16*)(ws + 39845888);      //  8 MB [1024][4096]
  bf16* qb   = (bf16*)(ws + 48234496);      //  8 MB [4096][1024]  (reused: FFN2 partial 0)
  bf16* kb   = (bf16*)(ws + 56623104);      //  8 MB [4096][1024]  (reused: FFN2 partial 1)
  bf16* vt   = (bf16*)(ws + 65011712);      //  8 MB [b,h,d,t] = [2048][2048] (reused: FFN2 partial 2)
  bf16* act  = (bf16*)(ws + 73400320);      // 32 MB [4096][4096]

  static bool s_attr_done = false;
  if (!s_attr_done) {
    hipFuncSetAttribute(reinterpret_cast<const void*>(gemm_qkv),
                        hipFuncAttributeMaxDynamicSharedMemorySize, 131072);
    hipFuncSetAttribute(reinterpret_cast<const void*>(gemm_ffn1),
                        hipFuncAttributeMaxDynamicSharedMemorySize, 131072);
    hipFuncSetAttribute(reinterpret_cast<const void*>(gemm_ffn2),
                        hipFuncAttributeMaxDynamicSharedMemorySize, 131072);
    s_attr_done = true;
  }

  transpose_all<<<11264, 256, 0, stream>>>(Wq, Wk, Wv, W1, W2, WqkT, W1T, W2T);
  ln_kernel<<<4096, 256, 0, stream>>>(x, ln1g, ln1b, h);
  gemm_qkv<<<dim3(12, 16), 512, 131072, stream>>>(h, WqkT, bq, bk, bv, qb, kb, vt, 1024);
  attn_mfma<<<dim3(32, 16), 512, 0, stream>>>(qb, kb, vt, x, x1);
  ln_kernel<<<4096, 256, 0, stream>>>(x1, ln2g, ln2b, h);
  gemm_ffn1<<<dim3(16, 16), 512, 131072, stream>>>(h, W1T, b1, act, 4096, 1024);
  gemm_ffn2<<<dim3(4, 16, 4), 512, 131072, stream>>>(act, W2T,
      (unsigned short*)qb, (unsigned short*)kb, (unsigned short*)vt, (unsigned short*)h);
  reduce_ffn2<<<4096, 256, 0, stream>>>((const unsigned short*)qb, (const unsigned short*)kb,
                                        (const unsigned short*)vt, (const unsigned short*)h,
                                        x1, b2, (float*)d_out);
}

// Round 4
// 295.888 us; speedup vs baseline: 1.2662x; 1.2662x over previous
//
#include <hip/hip_runtime.h>
#include <hip/hip_bf16.h>
#include <math.h>

typedef __hip_bfloat16 bf16;
typedef __attribute__((ext_vector_type(8))) short bf16x8;
typedef __attribute__((ext_vector_type(4))) float f32x4;

__device__ __forceinline__ unsigned short f2bf_rne(float f) {
  unsigned u = __float_as_uint(f);
  u += 0x7fffu + ((u >> 16) & 1u);
  return (unsigned short)(u >> 16);
}
__device__ __forceinline__ float bf2f(unsigned short s) {
  return __uint_as_float(((unsigned)s) << 16);
}

// fast tanh-form GELU: max |diff| vs exact erf-GELU ~1e-3
__device__ __forceinline__ float gelu_fast(float v) {
  float u = v * (0.7978845608f + 0.0356774081f * v * v);
  float t = __builtin_amdgcn_exp2f(u * 2.8853900818f);
  float r = __builtin_amdgcn_rcpf(t + 1.0f);
  return v - v * r;
}

#define GLOBAL_AS __attribute__((address_space(1)))
#define LDS_AS __attribute__((address_space(3)))
__device__ __forceinline__ void gl2lds16(const void* g, void* l) {
  __builtin_amdgcn_global_load_lds((const GLOBAL_AS void*)g, (LDS_AS void*)l, 16, 0, 0);
}

// ---------------- LayerNorm: x f32 [rows][1024] -> h bf16 ----------------
__global__ __launch_bounds__(256) void ln_kernel(const float* __restrict__ x,
                                                 const float* __restrict__ g,
                                                 const float* __restrict__ b,
                                                 bf16* __restrict__ h) {
  int row = blockIdx.x, t = threadIdx.x;
  const float4 xv = ((const float4*)(x + (size_t)row * 1024))[t];
  float s = xv.x + xv.y + xv.z + xv.w;
  float sq = xv.x * xv.x + xv.y * xv.y + xv.z * xv.z + xv.w * xv.w;
  #pragma unroll
  for (int m = 1; m < 64; m <<= 1) { s += __shfl_xor(s, m); sq += __shfl_xor(sq, m); }
  __shared__ float ps[4], pq[4];
  if ((t & 63) == 0) { ps[t >> 6] = s; pq[t >> 6] = sq; }
  __syncthreads();
  s = ps[0] + ps[1] + ps[2] + ps[3];
  sq = pq[0] + pq[1] + pq[2] + pq[3];
  float mean = s * (1.0f / 1024.0f);
  float var = sq * (1.0f / 1024.0f) - mean * mean;
  float rs = rsqrtf(var + 1e-3f);
  float4 gv = ((const float4*)g)[t];
  float4 bv = ((const float4*)b)[t];
  ushort4 o;
  o.x = f2bf_rne((xv.x - mean) * rs * gv.x + bv.x);
  o.y = f2bf_rne((xv.y - mean) * rs * gv.y + bv.y);
  o.z = f2bf_rne((xv.z - mean) * rs * gv.z + bv.z);
  o.w = f2bf_rne((xv.w - mean) * rs * gv.w + bv.w);
  ((ushort4*)(h + (size_t)row * 1024))[t] = o;
}

// ------------- merged transpose + f32->bf16 for all 5 weights -------------
__device__ __forceinline__ void tr_tile(const float* __restrict__ W, bf16* __restrict__ WT,
                                        int R, int Cc, int bx, int by, int t) {
  __shared__ float tile[32][33];
  int tx = t & 31, ty = t >> 5;
  #pragma unroll
  for (int k = 0; k < 4; k++) {
    int rr = ty + k * 8;
    tile[rr][tx] = W[(size_t)(by + rr) * Cc + bx + tx];
  }
  __syncthreads();
  unsigned short* out = reinterpret_cast<unsigned short*>(WT);
  #pragma unroll
  for (int k = 0; k < 4; k++) {
    int rr = ty + k * 8;
    out[(size_t)(bx + rr) * R + by + tx] = f2bf_rne(tile[tx][rr]);
  }
}

__global__ __launch_bounds__(256) void transpose_all(const float* __restrict__ Wq,
                                                     const float* __restrict__ Wk,
                                                     const float* __restrict__ Wv,
                                                     const float* __restrict__ W1,
                                                     const float* __restrict__ W2,
                                                     bf16* __restrict__ WqkT,
                                                     bf16* __restrict__ W1T,
                                                     bf16* __restrict__ W2T) {
  int id = blockIdx.x, t = threadIdx.x;
  if (id < 3072) {
    int sect = id >> 10, r = id & 1023;
    const float* W = sect == 0 ? Wq : (sect == 1 ? Wk : Wv);
    bf16* WT = WqkT + (size_t)sect * 1048576;
    tr_tile(W, WT, 1024, 1024, (r & 31) * 32, (r >> 5) * 32, t);
  } else if (id < 7168) {
    int r = id - 3072;
    tr_tile(W1, W1T, 1024, 4096, (r & 127) * 32, (r >> 7) * 32, t);
  } else {
    int r = id - 7168;
    tr_tile(W2, W2T, 4096, 1024, (r & 31) * 32, (r >> 5) * 32, t);
  }
}

// ============ 256x256 8-phase GEMM mainloop (T2+T3+T4+T5) ============
// BK=64, 512 threads (8 waves, 2Mx4N), per-wave 128x64 out, LDS 128KB:
// [A0 32K | B0 32K | A1 32K | B1 32K], tile kt -> buffer kt&1.
// Per iteration (2 K-tiles, 8 phases): phase = {ds_read subtile, stage 1
// half-tile, s_barrier, lgkmcnt(0), setprio(1) 16xMFMA setprio(0), barrier}.
// Counted vmcnt(4) ONLY at phases 4 and 8: tile t+1 landed, tile t+2's B
// stays in flight across the barrier. Stage slots: p1,p2=(t+1).A->nxt;
// p3,p4=(t+2).B->cur; p5,p6=(t+2).A->cur; p7,p8=(t+3).B->nxt. Each target
// half was last ds_read >=1 barrier earlier (freed).
// lda = row stride of A/BT (elements); nk = K-extent to process (multiple
// of 128). Caller pre-offsets A/BT for split-K slices.
__device__ __forceinline__ void mainloop_256(const bf16* __restrict__ A,
                                             const bf16* __restrict__ BT,
                                             int lda, int nk, int m0, int n0,
                                             char* ldsb, int t,
                                             f32x4 (&acc)[8][4]) {
  const int lane = t & 63, wave = t >> 6;
  const int l = lane & 15, quad = lane >> 4;
  const int wm = (wave >> 2) * 128, wn = (wave & 3) * 64;
  const int srow = wave * 8 + (lane >> 3);          // row within 64-row round
  const int scol = ((lane & 7) ^ (lane >> 3)) * 8;  // pre-swizzled global col
  const int grp0 = (quad ^ (l & 7)) * 16;           // swizzled 16B group, k-slice 0
  const int grp1 = ((4 + quad) ^ (l & 7)) * 16;     // k-slice 1

  bf16x8 a[4][2], b01[2][2], b23[2][2];

  auto stA = [&](int buf, int half, int kt) {
    const bf16* s = A + (size_t)(m0 + half * 128 + srow) * lda + kt * 64 + scol;
    char* d = ldsb + buf * 65536 + half * 16384 + wave * 1024;
    gl2lds16(s, d);
    gl2lds16(s + (size_t)64 * lda, d + 8192);
  };
  auto stB = [&](int buf, int half, int kt) {
    const bf16* s = BT + (size_t)(n0 + half * 128 + srow) * lda + kt * 64 + scol;
    char* d = ldsb + buf * 65536 + 32768 + half * 16384 + wave * 1024;
    gl2lds16(s, d);
    gl2lds16(s + (size_t)64 * lda, d + 8192);
  };
  auto rdA = [&](int buf, int mh) {
    const char* base = ldsb + buf * 65536 + (wm + mh * 64 + l) * 128;
    #pragma unroll
    for (int ii = 0; ii < 4; ii++) {
      a[ii][0] = *(const bf16x8*)(base + ii * 2048 + grp0);
      a[ii][1] = *(const bf16x8*)(base + ii * 2048 + grp1);
    }
  };
  auto rdB = [&](int buf, int nh, bf16x8 (&bb)[2][2]) {
    const char* base = ldsb + buf * 65536 + 32768 + (wn + nh * 32 + l) * 128;
    #pragma unroll
    for (int jj = 0; jj < 2; jj++) {
      bb[jj][0] = *(const bf16x8*)(base + jj * 2048 + grp0);
      bb[jj][1] = *(const bf16x8*)(base + jj * 2048 + grp1);
    }
  };
  auto mm4 = [&](int mi, bf16x8 (&bb)[2][2], int nj) {
    #pragma unroll
    for (int ii = 0; ii < 4; ii++)
      #pragma unroll
      for (int jj = 0; jj < 2; jj++) {
        acc[mi + ii][nj + jj] = __builtin_amdgcn_mfma_f32_16x16x32_bf16(
            a[ii][0], bb[jj][0], acc[mi + ii][nj + jj], 0, 0, 0);
        acc[mi + ii][nj + jj] = __builtin_amdgcn_mfma_f32_16x16x32_bf16(
            a[ii][1], bb[jj][1], acc[mi + ii][nj + jj], 0, 0, 0);
      }
  };

#define BARX() __builtin_amdgcn_s_barrier()
#define LGKM0() do { asm volatile("s_waitcnt lgkmcnt(0)" ::: "memory"); \
                     __builtin_amdgcn_sched_barrier(0); } while (0)
#define HALF4(BC, DOA, SAB, SAK, DOB, SBB, SBK, VMN)                      \
  do {                                                                    \
    rdA(BC, 0); rdB(BC, 0, b01);                                          \
    if (DOA) stA(SAB, 0, SAK);                                            \
    BARX(); LGKM0();                                                      \
    __builtin_amdgcn_s_setprio(1); mm4(0, b01, 0);                        \
    __builtin_amdgcn_s_setprio(0); BARX();                                \
    rdB(BC, 1, b23);                                                      \
    if (DOA) stA(SAB, 1, SAK);                                            \
    BARX(); LGKM0();                                                      \
    __builtin_amdgcn_s_setprio(1); mm4(0, b23, 2);                        \
    __builtin_amdgcn_s_setprio(0); BARX();                                \
    rdA(BC, 1);                                                           \
    if (DOB) stB(SBB, 0, SBK);                                            \
    BARX(); LGKM0();                                                      \
    __builtin_amdgcn_s_setprio(1); mm4(4, b01, 0);                        \
    __builtin_amdgcn_s_setprio(0); BARX();                                \
    if (DOB) stB(SBB, 1, SBK);                                            \
    BARX();                                                               \
    __builtin_amdgcn_s_setprio(1); mm4(4, b23, 2);                        \
    __builtin_amdgcn_s_setprio(0);                                        \
    asm volatile("s_waitcnt vmcnt(" VMN ")" ::: "memory");                \
    BARX();                                                               \
  } while (0)

  const int nt = nk >> 6;
  // prologue: tile0 (8 loads) + tile1.B (4 loads); vmcnt(4) -> tile0 landed
  stA(0, 0, 0); stA(0, 1, 0);
  stB(0, 0, 0); stB(0, 1, 0);
  stB(1, 0, 1); stB(1, 1, 1);
  asm volatile("s_waitcnt vmcnt(4)" ::: "memory");
  BARX();
  int tt = 0;
  for (; tt + 2 < nt; tt += 2) {
    HALF4(0, 1, 1, tt + 1, 1, 0, tt + 2, "4");
    HALF4(1, 1, 0, tt + 2, 1, 1, tt + 3, "4");
  }
  // tail: tt = nt-2; stage only (nt-1).A, drain fully before last tile
  HALF4(0, 1, 1, tt + 1, 0, 0, 0, "0");
  HALF4(1, 0, 0, 0, 0, 0, 0, "0");
#undef HALF4
#undef LGKM0
#undef BARX
}

// ---------------- FFN1: act bf16 = gelu(h @ W1 + b1), N=4096 K=1024 ---------
__global__ __launch_bounds__(512, 2) void gemm_ffn1(const bf16* __restrict__ A,
                                                    const bf16* __restrict__ BT,
                                                    const float* __restrict__ bias,
                                                    bf16* __restrict__ out,
                                                    int N, int K) {
  extern __shared__ char lds[];
  int t = threadIdx.x;
  int n0 = blockIdx.x * 256, m0 = blockIdx.y * 256;
  f32x4 acc[8][4];
  #pragma unroll
  for (int i = 0; i < 8; i++)
    #pragma unroll
    for (int j = 0; j < 4; j++) acc[i][j] = (f32x4){0.f, 0.f, 0.f, 0.f};
  mainloop_256(A, BT, K, K, m0, n0, lds, t, acc);

  int lane = t & 63, wave = t >> 6;
  int l = lane & 15, quad = lane >> 4;
  int wm = (wave >> 2) * 128, wn = (wave & 3) * 64;
  int r4 = quad * 4;
  unsigned short* os = reinterpret_cast<unsigned short*>(out);
  #pragma unroll
  for (int i = 0; i < 8; i++)
    #pragma unroll
    for (int j = 0; j < 4; j++) {
      int col = n0 + wn + j * 16 + l;
      float bval = bias[col];
      #pragma unroll
      for (int r = 0; r < 4; r++) {
        int row = m0 + wm + i * 16 + r4 + r;
        os[(size_t)row * N + col] = f2bf_rne(gelu_fast(acc[i][j][r] + bval));
      }
    }
}

// ------- FFN2 split-K (8-phase): partial[z] bf16 = act[:,z] @ W2T[:,z] ------
// M=4096 N=1024 K=4096, z in 0..3 each K=1024; grid (4,16,4)=256 blocks
// = 1 block/CU (128KB LDS). lda=4096, per-slice nk=1024 (nt=16, same as FFN1).
__global__ __launch_bounds__(512, 2) void gemm_ffn2(const bf16* __restrict__ A,
                                                    const bf16* __restrict__ BT,
                                                    unsigned short* __restrict__ p0,
                                                    unsigned short* __restrict__ p1,
                                                    unsigned short* __restrict__ p2,
                                                    unsigned short* __restrict__ p3) {
  extern __shared__ char lds[];
  int t = threadIdx.x;
  int n0 = blockIdx.x * 256, m0 = blockIdx.y * 256;
  int z = blockIdx.z;
  f32x4 acc[8][4];
  #pragma unroll
  for (int i = 0; i < 8; i++)
    #pragma unroll
    for (int j = 0; j < 4; j++) acc[i][j] = (f32x4){0.f, 0.f, 0.f, 0.f};
  mainloop_256(A + z * 1024, BT + z * 1024, 4096, 1024, m0, n0, lds, t, acc);

  unsigned short* p = z == 0 ? p0 : (z == 1 ? p1 : (z == 2 ? p2 : p3));
  int lane = t & 63, wave = t >> 6;
  int l = lane & 15, quad = lane >> 4;
  int wm = (wave >> 2) * 128, wn = (wave & 3) * 64;
  int r4 = quad * 4;
  #pragma unroll
  for (int i = 0; i < 8; i++)
    #pragma unroll
    for (int j = 0; j < 4; j++) {
      int col = n0 + wn + j * 16 + l;
      #pragma unroll
      for (int r = 0; r < 4; r++) {
        int row = m0 + wm + i * 16 + r4 + r;
        p[(size_t)row * 1024 + col] = f2bf_rne(acc[i][j][r]);
      }
    }
}

// -------- FFN2 reduce: out f32 = p0 + p1 + p2 + p3 + bias + x1 --------
__global__ __launch_bounds__(256) void reduce_ffn2(const unsigned short* __restrict__ p0,
                                                   const unsigned short* __restrict__ p1,
                                                   const unsigned short* __restrict__ p2,
                                                   const unsigned short* __restrict__ p3,
                                                   const float* __restrict__ x1,
                                                   const float* __restrict__ bias,
                                                   float* __restrict__ out) {
  int row = blockIdx.x, t = threadIdx.x;
  size_t base = (size_t)row * 1024;
  ushort4 a = ((const ushort4*)(p0 + base))[t];
  ushort4 b = ((const ushort4*)(p1 + base))[t];
  ushort4 c = ((const ushort4*)(p2 + base))[t];
  ushort4 d = ((const ushort4*)(p3 + base))[t];
  float4 xv = ((const float4*)(x1 + base))[t];
  float4 bv = ((const float4*)bias)[t];
  float4 o;
  o.x = (bf2f(a.x) + bf2f(b.x)) + (bf2f(c.x) + bf2f(d.x)) + xv.x + bv.x;
  o.y = (bf2f(a.y) + bf2f(b.y)) + (bf2f(c.y) + bf2f(d.y)) + xv.y + bv.y;
  o.z = (bf2f(a.z) + bf2f(b.z)) + (bf2f(c.z) + bf2f(d.z)) + xv.z + bv.z;
  o.w = (bf2f(a.w) + bf2f(b.w)) + (bf2f(c.w) + bf2f(d.w)) + xv.w + bv.w;
  ((float4*)(out + base))[t] = o;
}

// ------------- fused QKV GEMM: N=3072 (q|k|v); v written transposed ----------
__global__ __launch_bounds__(512, 2) void gemm_qkv(const bf16* __restrict__ A,
                                                   const bf16* __restrict__ BT,
                                                   const float* __restrict__ bq,
                                                   const float* __restrict__ bk,
                                                   const float* __restrict__ bv,
                                                   bf16* __restrict__ qb,
                                                   bf16* __restrict__ kb,
                                                   bf16* __restrict__ vt,
                                                   int K) {
  extern __shared__ char lds[];
  int t = threadIdx.x;
  int n0 = blockIdx.x * 256, m0 = blockIdx.y * 256;
  f32x4 acc[8][4];
  #pragma unroll
  for (int i = 0; i < 8; i++)
    #pragma unroll
    for (int j = 0; j < 4; j++) acc[i][j] = (f32x4){0.f, 0.f, 0.f, 0.f};
  mainloop_256(A, BT, K, K, m0, n0, lds, t, acc);

  int lane = t & 63, wave = t >> 6;
  int l = lane & 15, quad = lane >> 4;
  int wm = (wave >> 2) * 128, wn = (wave & 3) * 64;
  int sect = n0 >> 10;  // 0=q 1=k 2=v (BN=256 divides 1024 sections)
  const float* bias = sect == 0 ? bq : (sect == 1 ? bk : bv);
  int r4 = quad * 4;
  #pragma unroll
  for (int i = 0; i < 8; i++)
    #pragma unroll
    for (int j = 0; j < 4; j++) {
      int col = n0 + wn + j * 16 + l;
      int c1 = col & 1023;
      float bval = bias[c1];
      int row0 = m0 + wm + i * 16 + r4;
      if (sect < 2) {
        bf16* o = sect == 0 ? qb : kb;
        unsigned short* os = reinterpret_cast<unsigned short*>(o);
        #pragma unroll
        for (int r = 0; r < 4; r++)
          os[(size_t)(row0 + r) * 1024 + c1] = f2bf_rne(acc[i][j][r] + bval);
      } else {
        int hh = c1 >> 6, d = c1 & 63;
        int b = row0 >> 11, t0 = row0 & 2047;
        ushort4 pk;
        pk.x = f2bf_rne(acc[i][j][0] + bval);
        pk.y = f2bf_rne(acc[i][j][1] + bval);
        pk.z = f2bf_rne(acc[i][j][2] + bval);
        pk.w = f2bf_rne(acc[i][j][3] + bval);
        *(ushort4*)((unsigned short*)vt + (size_t)((b * 16 + hh) * 64 + d) * 2048 + t0) = pk;
      }
    }
}

// ---------------- MFMA flash attention v6 ----------------
// v4 staged structure (global_load_lds KV double-buffer + prefetch), but:
//  - ONE i-tile per block, grid (32 bh, 32 y) = 1024 blocks.
//  - Balanced largest-first it-map: y=8k+r -> it={31-r,16+r,15-r,r}[k];
//    every CU's 4 resident blocks sum to exactly 66 j-units.
//  - LDS exactly 40960B (QP [64][64] XOR-swizzled, staged via gl2lds)
//    -> 4 blocks/CU co-resident = 4 waves/SIMD (v4 was 2).
//  - P quad-exchange own-wave (ds_write -> lgkmcnt(0) -> ds_read), swizzled.
__global__ __launch_bounds__(256, 4) void attn_mfma(const bf16* __restrict__ qb,
                                                    const bf16* __restrict__ kb,
                                                    const bf16* __restrict__ vt,
                                                    const float* __restrict__ x,
                                                    float* __restrict__ x1) {
  __shared__ bf16 QP[64][64];        // Q in prologue, then P (XOR-swizzled)
  __shared__ bf16 KV[2][2][64][64];  // [buf][0=K,1=V], XOR-swizzled 16B groups
  int t = threadIdx.x;
  int bh = blockIdx.x;
  int b = bh >> 4, h = bh & 15;
  size_t qk_base = (size_t)b * 2048 * 1024 + (size_t)h * 64;
  size_t vt_base = (size_t)bh * 64 * 2048;
  int lane = t & 63, wave = t >> 6;
  int l = lane & 15, quad = lane >> 4;
  int sw = l & 7;
  int srow8 = lane >> 3;                       // staging row-in-8 (0..7)
  int scol = ((lane & 7) ^ srow8) * 8;         // swizzled source col (elems)
  const float cs = 0.125f * 1.44269504088896f; // scale * log2(e)
  int y = blockIdx.y;
  int yr = y & 7, yk = y >> 3;
  int it = yk == 0 ? 31 - yr : (yk == 1 ? 16 + yr : (yk == 2 ? 15 - yr : yr));
  int i0 = it * 64;
  int njt = it + 1;
  int iblk = i0 + wave * 16;

  // stage Q (own-wave rows, swizzled) + KV tile 0 into buf 0 (async)
  #pragma unroll
  for (int c = 0; c < 2; c++) {
    int rr = wave * 16 + c * 8 + srow8;
    gl2lds16(kb + qk_base + (size_t)(i0 + rr) * 1024 + scol,
             (char*)QP + wave * 2048 + c * 1024);
    gl2lds16(qb + qk_base + (size_t)rr * 1024 + scol,
             (char*)KV + wave * 2048 + c * 1024);
    gl2lds16(vt + vt_base + (size_t)rr * 2048 + scol,
             (char*)KV + 8192 + wave * 2048 + c * 1024);
  }
  __syncthreads();  // drains vmcnt: Q + KV0 visible to all waves

  const char* qr = (const char*)&QP[wave * 16 + l][0];
  bf16x8 qf0 = *(const bf16x8*)(qr + ((quad ^ sw) * 16));
  bf16x8 qf1 = *(const bf16x8*)(qr + (((4 + quad) ^ sw) * 16));
  float lsum = 0.f;
  f32x4 Oacc[4];
  #pragma unroll
  for (int dt = 0; dt < 4; dt++) Oacc[dt] = (f32x4){0.f, 0.f, 0.f, 0.f};

  char* Pw = (char*)&QP[wave * 16 + l][0];  // own-wave P row base

  int buf = 0;
  for (int jt = 0; jt < njt; jt++) {
    int j0v = jt * 64;
    // prefetch next KV tile into other buffer (overlaps with compute below)
    if (jt + 1 < njt) {
      int j1 = j0v + 64;
      #pragma unroll
      for (int c = 0; c < 2; c++) {
        int rr = wave * 16 + c * 8 + srow8;
        gl2lds16(qb + qk_base + (size_t)(j1 + rr) * 1024 + scol,
                 (char*)KV + (buf ^ 1) * 16384 + wave * 2048 + c * 1024);
        gl2lds16(vt + vt_base + (size_t)rr * 2048 + j1 + scol,
                 (char*)KV + (buf ^ 1) * 16384 + 8192 + wave * 2048 + c * 1024);
      }
    }

    // S^T per nt: A = K rows (m=j), B = Q frag (n=i)
    const bf16* Kb = &KV[buf][0][0][0];
    #pragma unroll
    for (int nt = 0; nt < 4; nt++) {
      int jb = j0v + nt * 16;
      uint2 pk;
      if (jb > iblk + 15) {  // fully masked
        pk.x = 0u; pk.y = 0u;
      } else {
        const bf16* kr = Kb + (nt * 16 + l) * 64;
        bf16x8 kf0 = *(const bf16x8*)(kr + ((quad ^ sw) * 8));
        bf16x8 kf1 = *(const bf16x8*)(kr + (((4 + quad) ^ sw) * 8));
        f32x4 sv = (f32x4){0.f, 0.f, 0.f, 0.f};
        sv = __builtin_amdgcn_mfma_f32_16x16x32_bf16(kf0, qf0, sv, 0, 0, 0);
        sv = __builtin_amdgcn_mfma_f32_16x16x32_bf16(kf1, qf1, sv, 0, 0, 0);
        float p0, p1, p2, p3;
        if (jb + 15 <= iblk) {  // fully unmasked
          p0 = __builtin_amdgcn_exp2f(sv[0] * cs);
          p1 = __builtin_amdgcn_exp2f(sv[1] * cs);
          p2 = __builtin_amdgcn_exp2f(sv[2] * cs);
          p3 = __builtin_amdgcn_exp2f(sv[3] * cs);
        } else {                // diagonal straddle
          int i_ = iblk + l, jbase = jb + quad * 4;
          p0 = (jbase + 0 > i_) ? 0.f : __builtin_amdgcn_exp2f(sv[0] * cs);
          p1 = (jbase + 1 > i_) ? 0.f : __builtin_amdgcn_exp2f(sv[1] * cs);
          p2 = (jbase + 2 > i_) ? 0.f : __builtin_amdgcn_exp2f(sv[2] * cs);
          p3 = (jbase + 3 > i_) ? 0.f : __builtin_amdgcn_exp2f(sv[3] * cs);
        }
        lsum += (p0 + p1) + (p2 + p3);
        union { __hip_bfloat162 h2; unsigned u; } c0u, c1u;
        c0u.h2 = __float22bfloat162_rn(make_float2(p0, p1));
        c1u.h2 = __float22bfloat162_rn(make_float2(p2, p3));
        pk.x = c0u.u; pk.y = c1u.u;
      }
      // P row byte offset nt*32+quad*8 -> 16B group g=nt*2+(quad>>1),
      // swizzled to (g^sw), byte-in-group (quad&1)*8
      *(uint2*)(Pw + (((nt * 2 + (quad >> 1)) ^ sw) << 4) + ((quad & 1) << 3)) = pk;
    }
    asm volatile("s_waitcnt lgkmcnt(0)" ::: "memory");  // own-wave P only

    // PV: A = P rows (m=i), B = V rows (n=d)
    bf16x8 ap0 = *(const bf16x8*)(Pw + ((quad ^ sw) << 4));
    bf16x8 ap1 = *(const bf16x8*)(Pw + (((4 + quad) ^ sw) << 4));
    const bf16* Vb = &KV[buf][1][0][0];
    #pragma unroll
    for (int dt = 0; dt < 4; dt++) {
      const bf16* vr = Vb + (dt * 16 + l) * 64;
      bf16x8 bv0 = *(const bf16x8*)(vr + ((quad ^ sw) * 8));
      bf16x8 bv1 = *(const bf16x8*)(vr + (((4 + quad) ^ sw) * 8));
      Oacc[dt] = __builtin_amdgcn_mfma_f32_16x16x32_bf16(ap0, bv0, Oacc[dt], 0, 0, 0);
      Oacc[dt] = __builtin_amdgcn_mfma_f32_16x16x32_bf16(ap1, bv1, Oacc[dt], 0, 0, 0);
    }
    __syncthreads();  // drains prefetch (vmcnt) + all waves done with buf
    buf ^= 1;
  }

  // denominator: sum over quads (each lane's lsum is i=l partial)
  lsum += __shfl_xor(lsum, 16);
  lsum += __shfl_xor(lsum, 32);
  #pragma unroll
  for (int r = 0; r < 4; r++) {
    float lv = __shfl(lsum, quad * 4 + r);
    float inv = 1.0f / lv;
    int row = iblk + quad * 4 + r;
    size_t gi = qk_base + (size_t)row * 1024;
    #pragma unroll
    for (int dt = 0; dt < 4; dt++) {
      int d = dt * 16 + l;
      x1[gi + d] = x[gi + d] + Oacc[dt][r] * inv;
    }
  }
}

extern "C" void kernel_launch(void* const* d_in, const int* in_sizes, int n_in,
                              void* d_out, int out_size, void* d_ws, size_t ws_size,
                              hipStream_t stream) {
  const float* x    = (const float*)d_in[0];
  const float* ln1g = (const float*)d_in[1];
  const float* ln1b = (const float*)d_in[2];
  const float* Wq   = (const float*)d_in[3];
  const float* bq   = (const float*)d_in[4];
  const float* Wk   = (const float*)d_in[5];
  const float* bk   = (const float*)d_in[6];
  const float* Wv   = (const float*)d_in[7];
  const float* bv   = (const float*)d_in[8];
  const float* ln2g = (const float*)d_in[9];
  const float* ln2b = (const float*)d_in[10];
  const float* W1   = (const float*)d_in[11];
  const float* b1   = (const float*)d_in[12];
  const float* W2   = (const float*)d_in[13];
  const float* b2   = (const float*)d_in[14];

  char* ws = (char*)d_ws;
  float* x1  = (float*)(ws + 0);            // 16 MB f32 [4096][1024]
  bf16* h    = (bf16*)(ws + 16777216);      //  8 MB bf16 [4096][1024]  (reused: FFN2 partial 3)
  bf16* WqkT = (bf16*)(ws + 25165824);      //  6 MB bf16 [3072][1024] (q|k|v)
  bf16* W1T  = (bf16*)(ws + 31457280);      //  8 MB [4096][1024]
  bf16* W2T  = (bf16*)(ws + 39845888);      //  8 MB [1024][4096]
  bf16* qb   = (bf16*)(ws + 48234496);      //  8 MB [4096][1024]  (reused: FFN2 partial 0)
  bf16* kb   = (bf16*)(ws + 56623104);      //  8 MB [4096][1024]  (reused: FFN2 partial 1)
  bf16* vt   = (bf16*)(ws + 65011712);      //  8 MB [b,h,d,t] = [2048][2048] (reused: FFN2 partial 2)
  bf16* act  = (bf16*)(ws + 73400320);      // 32 MB [4096][4096]

  static bool s_attr_done = false;
  if (!s_attr_done) {
    hipFuncSetAttribute(reinterpret_cast<const void*>(gemm_qkv),
                        hipFuncAttributeMaxDynamicSharedMemorySize, 131072);
    hipFuncSetAttribute(reinterpret_cast<const void*>(gemm_ffn1),
                        hipFuncAttributeMaxDynamicSharedMemorySize, 131072);
    hipFuncSetAttribute(reinterpret_cast<const void*>(gemm_ffn2),
                        hipFuncAttributeMaxDynamicSharedMemorySize, 131072);
    s_attr_done = true;
  }

  transpose_all<<<11264, 256, 0, stream>>>(Wq, Wk, Wv, W1, W2, WqkT, W1T, W2T);
  ln_kernel<<<4096, 256, 0, stream>>>(x, ln1g, ln1b, h);
  gemm_qkv<<<dim3(12, 16), 512, 131072, stream>>>(h, WqkT, bq, bk, bv, qb, kb, vt, 1024);
  attn_mfma<<<dim3(32, 32), 256, 0, stream>>>(qb, kb, vt, x, x1);
  ln_kernel<<<4096, 256, 0, stream>>>(x1, ln2g, ln2b, h);
  gemm_ffn1<<<dim3(16, 16), 512, 131072, stream>>>(h, W1T, b1, act, 4096, 1024);
  gemm_ffn2<<<dim3(4, 16, 4), 512, 131072, stream>>>(act, W2T,
      (unsigned short*)qb, (unsigned short*)kb, (unsigned short*)vt, (unsigned short*)h);
  reduce_ffn2<<<4096, 256, 0, stream>>>((const unsigned short*)qb, (const unsigned short*)kb,
                                        (const unsigned short*)vt, (const unsigned short*)h,
                                        x1, b2, (float*)d_out);
}

// Round 5
// 289.781 us; speedup vs baseline: 1.2929x; 1.0211x over previous
//
#include <hip/hip_runtime.h>
#include <hip/hip_bf16.h>
#include <math.h>

typedef __hip_bfloat16 bf16;
typedef __attribute__((ext_vector_type(8))) short bf16x8;
typedef __attribute__((ext_vector_type(4))) float f32x4;

__device__ __forceinline__ unsigned short f2bf_rne(float f) {
  unsigned u = __float_as_uint(f);
  u += 0x7fffu + ((u >> 16) & 1u);
  return (unsigned short)(u >> 16);
}
__device__ __forceinline__ float bf2f(unsigned short s) {
  return __uint_as_float(((unsigned)s) << 16);
}

// fast tanh-form GELU: max |diff| vs exact erf-GELU ~1e-3
__device__ __forceinline__ float gelu_fast(float v) {
  float u = v * (0.7978845608f + 0.0356774081f * v * v);
  float t = __builtin_amdgcn_exp2f(u * 2.8853900818f);
  float r = __builtin_amdgcn_rcpf(t + 1.0f);
  return v - v * r;
}

#define GLOBAL_AS __attribute__((address_space(1)))
#define LDS_AS __attribute__((address_space(3)))
__device__ __forceinline__ void gl2lds16(const void* g, void* l) {
  __builtin_amdgcn_global_load_lds((const GLOBAL_AS void*)g, (LDS_AS void*)l, 16, 0, 0);
}

// ---------------- LayerNorm: x f32 [rows][1024] -> h bf16 ----------------
__global__ __launch_bounds__(256) void ln_kernel(const float* __restrict__ x,
                                                 const float* __restrict__ g,
                                                 const float* __restrict__ b,
                                                 bf16* __restrict__ h) {
  int row = blockIdx.x, t = threadIdx.x;
  const float4 xv = ((const float4*)(x + (size_t)row * 1024))[t];
  float s = xv.x + xv.y + xv.z + xv.w;
  float sq = xv.x * xv.x + xv.y * xv.y + xv.z * xv.z + xv.w * xv.w;
  #pragma unroll
  for (int m = 1; m < 64; m <<= 1) { s += __shfl_xor(s, m); sq += __shfl_xor(sq, m); }
  __shared__ float ps[4], pq[4];
  if ((t & 63) == 0) { ps[t >> 6] = s; pq[t >> 6] = sq; }
  __syncthreads();
  s = ps[0] + ps[1] + ps[2] + ps[3];
  sq = pq[0] + pq[1] + pq[2] + pq[3];
  float mean = s * (1.0f / 1024.0f);
  float var = sq * (1.0f / 1024.0f) - mean * mean;
  float rs = rsqrtf(var + 1e-3f);
  float4 gv = ((const float4*)g)[t];
  float4 bv = ((const float4*)b)[t];
  ushort4 o;
  o.x = f2bf_rne((xv.x - mean) * rs * gv.x + bv.x);
  o.y = f2bf_rne((xv.y - mean) * rs * gv.y + bv.y);
  o.z = f2bf_rne((xv.z - mean) * rs * gv.z + bv.z);
  o.w = f2bf_rne((xv.w - mean) * rs * gv.w + bv.w);
  ((ushort4*)(h + (size_t)row * 1024))[t] = o;
}

// ------------- merged transpose + f32->bf16 for all 5 weights -------------
__device__ __forceinline__ void tr_tile(const float* __restrict__ W, bf16* __restrict__ WT,
                                        int R, int Cc, int bx, int by, int t) {
  __shared__ float tile[32][33];
  int tx = t & 31, ty = t >> 5;
  #pragma unroll
  for (int k = 0; k < 4; k++) {
    int rr = ty + k * 8;
    tile[rr][tx] = W[(size_t)(by + rr) * Cc + bx + tx];
  }
  __syncthreads();
  unsigned short* out = reinterpret_cast<unsigned short*>(WT);
  #pragma unroll
  for (int k = 0; k < 4; k++) {
    int rr = ty + k * 8;
    out[(size_t)(bx + rr) * R + by + tx] = f2bf_rne(tile[tx][rr]);
  }
}

__global__ __launch_bounds__(256) void transpose_all(const float* __restrict__ Wq,
                                                     const float* __restrict__ Wk,
                                                     const float* __restrict__ Wv,
                                                     const float* __restrict__ W1,
                                                     const float* __restrict__ W2,
                                                     bf16* __restrict__ WqkT,
                                                     bf16* __restrict__ W1T,
                                                     bf16* __restrict__ W2T) {
  int id = blockIdx.x, t = threadIdx.x;
  if (id < 3072) {
    int sect = id >> 10, r = id & 1023;
    const float* W = sect == 0 ? Wq : (sect == 1 ? Wk : Wv);
    bf16* WT = WqkT + (size_t)sect * 1048576;
    tr_tile(W, WT, 1024, 1024, (r & 31) * 32, (r >> 5) * 32, t);
  } else if (id < 7168) {
    int r = id - 3072;
    tr_tile(W1, W1T, 1024, 4096, (r & 127) * 32, (r >> 7) * 32, t);
  } else {
    int r = id - 7168;
    tr_tile(W2, W2T, 4096, 1024, (r & 31) * 32, (r >> 5) * 32, t);
  }
}

// ============ 256x256 8-phase GEMM mainloop (T2+T3+T4+T5) ============
// (unchanged; see round-1 comment block for schedule derivation)
__device__ __forceinline__ void mainloop_256(const bf16* __restrict__ A,
                                             const bf16* __restrict__ BT,
                                             int lda, int nk, int m0, int n0,
                                             char* ldsb, int t,
                                             f32x4 (&acc)[8][4]) {
  const int lane = t & 63, wave = t >> 6;
  const int l = lane & 15, quad = lane >> 4;
  const int wm = (wave >> 2) * 128, wn = (wave & 3) * 64;
  const int srow = wave * 8 + (lane >> 3);          // row within 64-row round
  const int scol = ((lane & 7) ^ (lane >> 3)) * 8;  // pre-swizzled global col
  const int grp0 = (quad ^ (l & 7)) * 16;           // swizzled 16B group, k-slice 0
  const int grp1 = ((4 + quad) ^ (l & 7)) * 16;     // k-slice 1

  bf16x8 a[4][2], b01[2][2], b23[2][2];

  auto stA = [&](int buf, int half, int kt) {
    const bf16* s = A + (size_t)(m0 + half * 128 + srow) * lda + kt * 64 + scol;
    char* d = ldsb + buf * 65536 + half * 16384 + wave * 1024;
    gl2lds16(s, d);
    gl2lds16(s + (size_t)64 * lda, d + 8192);
  };
  auto stB = [&](int buf, int half, int kt) {
    const bf16* s = BT + (size_t)(n0 + half * 128 + srow) * lda + kt * 64 + scol;
    char* d = ldsb + buf * 65536 + 32768 + half * 16384 + wave * 1024;
    gl2lds16(s, d);
    gl2lds16(s + (size_t)64 * lda, d + 8192);
  };
  auto rdA = [&](int buf, int mh) {
    const char* base = ldsb + buf * 65536 + (wm + mh * 64 + l) * 128;
    #pragma unroll
    for (int ii = 0; ii < 4; ii++) {
      a[ii][0] = *(const bf16x8*)(base + ii * 2048 + grp0);
      a[ii][1] = *(const bf16x8*)(base + ii * 2048 + grp1);
    }
  };
  auto rdB = [&](int buf, int nh, bf16x8 (&bb)[2][2]) {
    const char* base = ldsb + buf * 65536 + 32768 + (wn + nh * 32 + l) * 128;
    #pragma unroll
    for (int jj = 0; jj < 2; jj++) {
      bb[jj][0] = *(const bf16x8*)(base + jj * 2048 + grp0);
      bb[jj][1] = *(const bf16x8*)(base + jj * 2048 + grp1);
    }
  };
  auto mm4 = [&](int mi, bf16x8 (&bb)[2][2], int nj) {
    #pragma unroll
    for (int ii = 0; ii < 4; ii++)
      #pragma unroll
      for (int jj = 0; jj < 2; jj++) {
        acc[mi + ii][nj + jj] = __builtin_amdgcn_mfma_f32_16x16x32_bf16(
            a[ii][0], bb[jj][0], acc[mi + ii][nj + jj], 0, 0, 0);
        acc[mi + ii][nj + jj] = __builtin_amdgcn_mfma_f32_16x16x32_bf16(
            a[ii][1], bb[jj][1], acc[mi + ii][nj + jj], 0, 0, 0);
      }
  };

#define BARX() __builtin_amdgcn_s_barrier()
#define LGKM0() do { asm volatile("s_waitcnt lgkmcnt(0)" ::: "memory"); \
                     __builtin_amdgcn_sched_barrier(0); } while (0)
#define HALF4(BC, DOA, SAB, SAK, DOB, SBB, SBK, VMN)                      \
  do {                                                                    \
    rdA(BC, 0); rdB(BC, 0, b01);                                          \
    if (DOA) stA(SAB, 0, SAK);                                            \
    BARX(); LGKM0();                                                      \
    __builtin_amdgcn_s_setprio(1); mm4(0, b01, 0);                        \
    __builtin_amdgcn_s_setprio(0); BARX();                                \
    rdB(BC, 1, b23);                                                      \
    if (DOA) stA(SAB, 1, SAK);                                            \
    BARX(); LGKM0();                                                      \
    __builtin_amdgcn_s_setprio(1); mm4(0, b23, 2);                        \
    __builtin_amdgcn_s_setprio(0); BARX();                                \
    rdA(BC, 1);                                                           \
    if (DOB) stB(SBB, 0, SBK);                                            \
    BARX(); LGKM0();                                                      \
    __builtin_amdgcn_s_setprio(1); mm4(4, b01, 0);                        \
    __builtin_amdgcn_s_setprio(0); BARX();                                \
    if (DOB) stB(SBB, 1, SBK);                                            \
    BARX();                                                               \
    __builtin_amdgcn_s_setprio(1); mm4(4, b23, 2);                        \
    __builtin_amdgcn_s_setprio(0);                                        \
    asm volatile("s_waitcnt vmcnt(" VMN ")" ::: "memory");                \
    BARX();                                                               \
  } while (0)

  const int nt = nk >> 6;
  // prologue: tile0 (8 loads) + tile1.B (4 loads); vmcnt(4) -> tile0 landed
  stA(0, 0, 0); stA(0, 1, 0);
  stB(0, 0, 0); stB(0, 1, 0);
  stB(1, 0, 1); stB(1, 1, 1);
  asm volatile("s_waitcnt vmcnt(4)" ::: "memory");
  BARX();
  int tt = 0;
  for (; tt + 2 < nt; tt += 2) {
    HALF4(0, 1, 1, tt + 1, 1, 0, tt + 2, "4");
    HALF4(1, 1, 0, tt + 2, 1, 1, tt + 3, "4");
  }
  // tail: tt = nt-2; stage only (nt-1).A, drain fully before last tile
  HALF4(0, 1, 1, tt + 1, 0, 0, 0, "0");
  HALF4(1, 0, 0, 0, 0, 0, 0, "0");
#undef HALF4
#undef LGKM0
#undef BARX
}

// ---------------- FFN1: act bf16 = gelu(h @ W1 + b1), N=4096 K=1024 ---------
__global__ __launch_bounds__(512, 2) void gemm_ffn1(const bf16* __restrict__ A,
                                                    const bf16* __restrict__ BT,
                                                    const float* __restrict__ bias,
                                                    bf16* __restrict__ out,
                                                    int N, int K) {
  extern __shared__ char lds[];
  int t = threadIdx.x;
  int n0 = blockIdx.x * 256, m0 = blockIdx.y * 256;
  f32x4 acc[8][4];
  #pragma unroll
  for (int i = 0; i < 8; i++)
    #pragma unroll
    for (int j = 0; j < 4; j++) acc[i][j] = (f32x4){0.f, 0.f, 0.f, 0.f};
  mainloop_256(A, BT, K, K, m0, n0, lds, t, acc);

  int lane = t & 63, wave = t >> 6;
  int l = lane & 15, quad = lane >> 4;
  int wm = (wave >> 2) * 128, wn = (wave & 3) * 64;
  int r4 = quad * 4;
  unsigned short* os = reinterpret_cast<unsigned short*>(out);
  #pragma unroll
  for (int i = 0; i < 8; i++)
    #pragma unroll
    for (int j = 0; j < 4; j++) {
      int col = n0 + wn + j * 16 + l;
      float bval = bias[col];
      #pragma unroll
      for (int r = 0; r < 4; r++) {
        int row = m0 + wm + i * 16 + r4 + r;
        os[(size_t)row * N + col] = f2bf_rne(gelu_fast(acc[i][j][r] + bval));
      }
    }
}

// ------- FFN2 split-K (8-phase): partial[z] bf16 = act[:,z] @ W2T[:,z] ------
__global__ __launch_bounds__(512, 2) void gemm_ffn2(const bf16* __restrict__ A,
                                                    const bf16* __restrict__ BT,
                                                    unsigned short* __restrict__ p0,
                                                    unsigned short* __restrict__ p1,
                                                    unsigned short* __restrict__ p2,
                                                    unsigned short* __restrict__ p3) {
  extern __shared__ char lds[];
  int t = threadIdx.x;
  int n0 = blockIdx.x * 256, m0 = blockIdx.y * 256;
  int z = blockIdx.z;
  f32x4 acc[8][4];
  #pragma unroll
  for (int i = 0; i < 8; i++)
    #pragma unroll
    for (int j = 0; j < 4; j++) acc[i][j] = (f32x4){0.f, 0.f, 0.f, 0.f};
  mainloop_256(A + z * 1024, BT + z * 1024, 4096, 1024, m0, n0, lds, t, acc);

  unsigned short* p = z == 0 ? p0 : (z == 1 ? p1 : (z == 2 ? p2 : p3));
  int lane = t & 63, wave = t >> 6;
  int l = lane & 15, quad = lane >> 4;
  int wm = (wave >> 2) * 128, wn = (wave & 3) * 64;
  int r4 = quad * 4;
  #pragma unroll
  for (int i = 0; i < 8; i++)
    #pragma unroll
    for (int j = 0; j < 4; j++) {
      int col = n0 + wn + j * 16 + l;
      #pragma unroll
      for (int r = 0; r < 4; r++) {
        int row = m0 + wm + i * 16 + r4 + r;
        p[(size_t)row * 1024 + col] = f2bf_rne(acc[i][j][r]);
      }
    }
}

// -------- FFN2 reduce: out f32 = p0 + p1 + p2 + p3 + bias + x1 --------
__global__ __launch_bounds__(256) void reduce_ffn2(const unsigned short* __restrict__ p0,
                                                   const unsigned short* __restrict__ p1,
                                                   const unsigned short* __restrict__ p2,
                                                   const unsigned short* __restrict__ p3,
                                                   const float* __restrict__ x1,
                                                   const float* __restrict__ bias,
                                                   float* __restrict__ out) {
  int row = blockIdx.x, t = threadIdx.x;
  size_t base = (size_t)row * 1024;
  ushort4 a = ((const ushort4*)(p0 + base))[t];
  ushort4 b = ((const ushort4*)(p1 + base))[t];
  ushort4 c = ((const ushort4*)(p2 + base))[t];
  ushort4 d = ((const ushort4*)(p3 + base))[t];
  float4 xv = ((const float4*)(x1 + base))[t];
  float4 bv = ((const float4*)bias)[t];
  float4 o;
  o.x = (bf2f(a.x) + bf2f(b.x)) + (bf2f(c.x) + bf2f(d.x)) + xv.x + bv.x;
  o.y = (bf2f(a.y) + bf2f(b.y)) + (bf2f(c.y) + bf2f(d.y)) + xv.y + bv.y;
  o.z = (bf2f(a.z) + bf2f(b.z)) + (bf2f(c.z) + bf2f(d.z)) + xv.z + bv.z;
  o.w = (bf2f(a.w) + bf2f(b.w)) + (bf2f(c.w) + bf2f(d.w)) + xv.w + bv.w;
  ((float4*)(out + base))[t] = o;
}

// ------------- fused QKV GEMM: N=3072 (q|k|v); v written transposed ----------
__global__ __launch_bounds__(512, 2) void gemm_qkv(const bf16* __restrict__ A,
                                                   const bf16* __restrict__ BT,
                                                   const float* __restrict__ bq,
                                                   const float* __restrict__ bk,
                                                   const float* __restrict__ bv,
                                                   bf16* __restrict__ qb,
                                                   bf16* __restrict__ kb,
                                                   bf16* __restrict__ vt,
                                                   int K) {
  extern __shared__ char lds[];
  int t = threadIdx.x;
  int n0 = blockIdx.x * 256, m0 = blockIdx.y * 256;
  f32x4 acc[8][4];
  #pragma unroll
  for (int i = 0; i < 8; i++)
    #pragma unroll
    for (int j = 0; j < 4; j++) acc[i][j] = (f32x4){0.f, 0.f, 0.f, 0.f};
  mainloop_256(A, BT, K, K, m0, n0, lds, t, acc);

  int lane = t & 63, wave = t >> 6;
  int l = lane & 15, quad = lane >> 4;
  int wm = (wave >> 2) * 128, wn = (wave & 3) * 64;
  int sect = n0 >> 10;  // 0=q 1=k 2=v (BN=256 divides 1024 sections)
  const float* bias = sect == 0 ? bq : (sect == 1 ? bk : bv);
  int r4 = quad * 4;
  #pragma unroll
  for (int i = 0; i < 8; i++)
    #pragma unroll
    for (int j = 0; j < 4; j++) {
      int col = n0 + wn + j * 16 + l;
      int c1 = col & 1023;
      float bval = bias[c1];
      int row0 = m0 + wm + i * 16 + r4;
      if (sect < 2) {
        bf16* o = sect == 0 ? qb : kb;
        unsigned short* os = reinterpret_cast<unsigned short*>(o);
        #pragma unroll
        for (int r = 0; r < 4; r++)
          os[(size_t)(row0 + r) * 1024 + c1] = f2bf_rne(acc[i][j][r] + bval);
      } else {
        int hh = c1 >> 6, d = c1 & 63;
        int b = row0 >> 11, t0 = row0 & 2047;
        ushort4 pk;
        pk.x = f2bf_rne(acc[i][j][0] + bval);
        pk.y = f2bf_rne(acc[i][j][1] + bval);
        pk.z = f2bf_rne(acc[i][j][2] + bval);
        pk.w = f2bf_rne(acc[i][j][3] + bval);
        *(ushort4*)((unsigned short*)vt + (size_t)((b * 16 + hh) * 64 + d) * 2048 + t0) = pk;
      }
    }
}

// ---------------- MFMA flash attention v7 ----------------
// One i-tile per block; 8 waves = 2 groups of 4. Group g processes j-tiles
// jt = g, g+2, ... with its OWN KV double-buffer (no cross-group sharing);
// both groups accumulate partial (O, lsum) for the SAME 64 i-rows; in-block
// combine through LDS at the end. Block duration = ceil(njt/2) -> longest
// block 16 units (was 32) -> occupancy tail halved. LDS 80KB = KV 64KB
// (2 groups x 2 bufs x (K 8KB + V 8KB)) + P 16KB (8 waves x [16][64]).
// Q staged once into P region, read to regs by all waves, then overlaid.
// 2 blocks/CU. Largest-first dispatch (it = 31 - y).
__global__ __launch_bounds__(512, 4) void attn_mfma(const bf16* __restrict__ qb,
                                                    const bf16* __restrict__ kb,
                                                    const bf16* __restrict__ vt,
                                                    const float* __restrict__ x,
                                                    float* __restrict__ x1) {
  extern __shared__ char alds[];
  char* KVb = alds;           // 64KB: g*32768 + buf*16384 + (K:0|V:8192) + w4*2048
  char* Pb  = alds + 65536;   // 16KB: wave*2048, row l stride 128B
  int t = threadIdx.x;
  int bh = blockIdx.x;
  int b = bh >> 4, h = bh & 15;
  size_t qk_base = (size_t)b * 2048 * 1024 + (size_t)h * 64;
  size_t vt_base = (size_t)bh * 64 * 2048;
  int lane = t & 63, wave = t >> 6;
  int g = wave >> 2, w4 = wave & 3;
  int l = lane & 15, quad = lane >> 4;
  int sw = l & 7;
  int srow8 = lane >> 3;                       // staging row-in-8 (0..7)
  int scol = ((lane & 7) ^ srow8) * 8;         // swizzled source col (elems)
  const float cs = 0.125f * 1.44269504088896f; // scale * log2(e)
  int it = 31 - blockIdx.y;                    // largest first
  int i0 = it * 64;
  int njt = it + 1;
  int iblk = i0 + w4 * 16;

  // prologue: waves 0-3 stage Q (into P region) + group0 KV tile0;
  // waves 4-7 stage group1 KV tile1 (if it exists)
  if (g == 0) {
    #pragma unroll
    for (int c = 0; c < 2; c++) {
      int rr = w4 * 16 + c * 8 + srow8;
      gl2lds16(kb + qk_base + (size_t)(i0 + rr) * 1024 + scol,
               Pb + w4 * 2048 + c * 1024);
      gl2lds16(qb + qk_base + (size_t)rr * 1024 + scol,
               KVb + w4 * 2048 + c * 1024);
      gl2lds16(vt + vt_base + (size_t)rr * 2048 + scol,
               KVb + 8192 + w4 * 2048 + c * 1024);
    }
  } else if (njt > 1) {
    #pragma unroll
    for (int c = 0; c < 2; c++) {
      int rr = w4 * 16 + c * 8 + srow8;
      gl2lds16(qb + qk_base + (size_t)(64 + rr) * 1024 + scol,
               KVb + 32768 + w4 * 2048 + c * 1024);
      gl2lds16(vt + vt_base + (size_t)rr * 2048 + 64 + scol,
               KVb + 32768 + 8192 + w4 * 2048 + c * 1024);
    }
  }
  __syncthreads();  // drains vmcnt: Q + first tiles visible

  const char* qr = Pb + w4 * 2048 + l * 128;
  bf16x8 qf0 = *(const bf16x8*)(qr + ((quad ^ sw) * 16));
  bf16x8 qf1 = *(const bf16x8*)(qr + (((4 + quad) ^ sw) * 16));
  __syncthreads();  // all waves hold Q in regs; P region may be overlaid now

  float lsum = 0.f;
  f32x4 Oacc[4];
  #pragma unroll
  for (int dt = 0; dt < 4; dt++) Oacc[dt] = (f32x4){0.f, 0.f, 0.f, 0.f};

  char* Pw = Pb + wave * 2048 + l * 128;  // own-wave P row base
  char* KVg = KVb + g * 32768;
  int nstep = (njt + 1) >> 1;
  int buf = 0;
  for (int s = 0; s < nstep; s++) {
    int jt = 2 * s + g;
    // prefetch my group's tile jt+2 into other buffer
    if (jt + 2 < njt) {
      int j1 = (jt + 2) * 64;
      #pragma unroll
      for (int c = 0; c < 2; c++) {
        int rr = w4 * 16 + c * 8 + srow8;
        gl2lds16(qb + qk_base + (size_t)(j1 + rr) * 1024 + scol,
                 KVg + (buf ^ 1) * 16384 + w4 * 2048 + c * 1024);
        gl2lds16(vt + vt_base + (size_t)rr * 2048 + j1 + scol,
                 KVg + (buf ^ 1) * 16384 + 8192 + w4 * 2048 + c * 1024);
      }
    }
    if (jt < njt) {
      int j0v = jt * 64;
      // S^T per nt: A = K rows (m=j), B = Q frag (n=i)
      const bf16* Kb = (const bf16*)(KVg + buf * 16384);
      #pragma unroll
      for (int nt = 0; nt < 4; nt++) {
        int jb = j0v + nt * 16;
        uint2 pk;
        if (jb > iblk + 15) {  // fully masked
          pk.x = 0u; pk.y = 0u;
        } else {
          const bf16* kr = Kb + (nt * 16 + l) * 64;
          bf16x8 kf0 = *(const bf16x8*)(kr + ((quad ^ sw) * 8));
          bf16x8 kf1 = *(const bf16x8*)(kr + (((4 + quad) ^ sw) * 8));
          f32x4 sv = (f32x4){0.f, 0.f, 0.f, 0.f};
          sv = __builtin_amdgcn_mfma_f32_16x16x32_bf16(kf0, qf0, sv, 0, 0, 0);
          sv = __builtin_amdgcn_mfma_f32_16x16x32_bf16(kf1, qf1, sv, 0, 0, 0);
          float p0, p1, p2, p3;
          if (jb + 15 <= iblk) {  // fully unmasked
            p0 = __builtin_amdgcn_exp2f(sv[0] * cs);
            p1 = __builtin_amdgcn_exp2f(sv[1] * cs);
            p2 = __builtin_amdgcn_exp2f(sv[2] * cs);
            p3 = __builtin_amdgcn_exp2f(sv[3] * cs);
          } else {                // diagonal straddle
            int i_ = iblk + l, jbase = jb + quad * 4;
            p0 = (jbase + 0 > i_) ? 0.f : __builtin_amdgcn_exp2f(sv[0] * cs);
            p1 = (jbase + 1 > i_) ? 0.f : __builtin_amdgcn_exp2f(sv[1] * cs);
            p2 = (jbase + 2 > i_) ? 0.f : __builtin_amdgcn_exp2f(sv[2] * cs);
            p3 = (jbase + 3 > i_) ? 0.f : __builtin_amdgcn_exp2f(sv[3] * cs);
          }
          lsum += (p0 + p1) + (p2 + p3);
          union { __hip_bfloat162 h2; unsigned u; } c0u, c1u;
          c0u.h2 = __float22bfloat162_rn(make_float2(p0, p1));
          c1u.h2 = __float22bfloat162_rn(make_float2(p2, p3));
          pk.x = c0u.u; pk.y = c1u.u;
        }
        // P row byte offset: 16B group g16=nt*2+(quad>>1) swizzled by sw
        *(uint2*)(Pw + (((nt * 2 + (quad >> 1)) ^ sw) << 4) + ((quad & 1) << 3)) = pk;
      }
      asm volatile("s_waitcnt lgkmcnt(0)" ::: "memory");  // own-wave P only

      // PV: A = P rows (m=i), B = V rows (n=d)
      bf16x8 ap0 = *(const bf16x8*)(Pw + ((quad ^ sw) << 4));
      bf16x8 ap1 = *(const bf16x8*)(Pw + (((4 + quad) ^ sw) << 4));
      const bf16* Vb = (const bf16*)(KVg + buf * 16384 + 8192);
      #pragma unroll
      for (int dt = 0; dt < 4; dt++) {
        const bf16* vr = Vb + (dt * 16 + l) * 64;
        bf16x8 bv0 = *(const bf16x8*)(vr + ((quad ^ sw) * 8));
        bf16x8 bv1 = *(const bf16x8*)(vr + (((4 + quad) ^ sw) * 8));
        Oacc[dt] = __builtin_amdgcn_mfma_f32_16x16x32_bf16(ap0, bv0, Oacc[dt], 0, 0, 0);
        Oacc[dt] = __builtin_amdgcn_mfma_f32_16x16x32_bf16(ap1, bv1, Oacc[dt], 0, 0, 0);
      }
    }
    __syncthreads();  // drains prefetch (vmcnt) + group done with buf
    buf ^= 1;
  }

  // in-block combine: group1 -> LDS (KV region now free) -> group0 adds
  float* F = (float*)KVb;
  int fbase = w4 * 1088;
  if (g == 1) {
    #pragma unroll
    for (int dt = 0; dt < 4; dt++)
      #pragma unroll
      for (int r = 0; r < 4; r++)
        F[fbase + (dt * 4 + r) * 64 + lane] = Oacc[dt][r];
    F[fbase + 1024 + lane] = lsum;
  }
  __syncthreads();
  if (g == 0) {
    #pragma unroll
    for (int dt = 0; dt < 4; dt++)
      #pragma unroll
      for (int r = 0; r < 4; r++)
        Oacc[dt][r] += F[fbase + (dt * 4 + r) * 64 + lane];
    lsum += F[fbase + 1024 + lane];
    // denominator: sum over quads (each lane's lsum is i=l partial)
    lsum += __shfl_xor(lsum, 16);
    lsum += __shfl_xor(lsum, 32);
    #pragma unroll
    for (int r = 0; r < 4; r++) {
      float lv = __shfl(lsum, quad * 4 + r);
      float inv = 1.0f / lv;
      int row = iblk + quad * 4 + r;
      size_t gi = qk_base + (size_t)row * 1024;
      #pragma unroll
      for (int dt = 0; dt < 4; dt++) {
        int d = dt * 16 + l;
        x1[gi + d] = x[gi + d] + Oacc[dt][r] * inv;
      }
    }
  }
}

extern "C" void kernel_launch(void* const* d_in, const int* in_sizes, int n_in,
                              void* d_out, int out_size, void* d_ws, size_t ws_size,
                              hipStream_t stream) {
  const float* x    = (const float*)d_in[0];
  const float* ln1g = (const float*)d_in[1];
  const float* ln1b = (const float*)d_in[2];
  const float* Wq   = (const float*)d_in[3];
  const float* bq   = (const float*)d_in[4];
  const float* Wk   = (const float*)d_in[5];
  const float* bk   = (const float*)d_in[6];
  const float* Wv   = (const float*)d_in[7];
  const float* bv   = (const float*)d_in[8];
  const float* ln2g = (const float*)d_in[9];
  const float* ln2b = (const float*)d_in[10];
  const float* W1   = (const float*)d_in[11];
  const float* b1   = (const float*)d_in[12];
  const float* W2   = (const float*)d_in[13];
  const float* b2   = (const float*)d_in[14];

  char* ws = (char*)d_ws;
  float* x1  = (float*)(ws + 0);            // 16 MB f32 [4096][1024]
  bf16* h    = (bf16*)(ws + 16777216);      //  8 MB bf16 [4096][1024]  (reused: FFN2 partial 3)
  bf16* WqkT = (bf16*)(ws + 25165824);      //  6 MB bf16 [3072][1024] (q|k|v)
  bf16* W1T  = (bf16*)(ws + 31457280);      //  8 MB [4096][1024]
  bf16* W2T  = (bf16*)(ws + 39845888);      //  8 MB [1024][4096]
  bf16* qb   = (bf16*)(ws + 48234496);      //  8 MB [4096][1024]  (reused: FFN2 partial 0)
  bf16* kb   = (bf16*)(ws + 56623104);      //  8 MB [4096][1024]  (reused: FFN2 partial 1)
  bf16* vt   = (bf16*)(ws + 65011712);      //  8 MB [b,h,d,t] = [2048][2048] (reused: FFN2 partial 2)
  bf16* act  = (bf16*)(ws + 73400320);      // 32 MB [4096][4096]

  static bool s_attr_done = false;
  if (!s_attr_done) {
    hipFuncSetAttribute(reinterpret_cast<const void*>(gemm_qkv),
                        hipFuncAttributeMaxDynamicSharedMemorySize, 131072);
    hipFuncSetAttribute(reinterpret_cast<const void*>(gemm_ffn1),
                        hipFuncAttributeMaxDynamicSharedMemorySize, 131072);
    hipFuncSetAttribute(reinterpret_cast<const void*>(gemm_ffn2),
                        hipFuncAttributeMaxDynamicSharedMemorySize, 131072);
    hipFuncSetAttribute(reinterpret_cast<const void*>(attn_mfma),
                        hipFuncAttributeMaxDynamicSharedMemorySize, 81920);
    s_attr_done = true;
  }

  transpose_all<<<11264, 256, 0, stream>>>(Wq, Wk, Wv, W1, W2, WqkT, W1T, W2T);
  ln_kernel<<<4096, 256, 0, stream>>>(x, ln1g, ln1b, h);
  gemm_qkv<<<dim3(12, 16), 512, 131072, stream>>>(h, WqkT, bq, bk, bv, qb, kb, vt, 1024);
  attn_mfma<<<dim3(32, 32), 512, 81920, stream>>>(qb, kb, vt, x, x1);
  ln_kernel<<<4096, 256, 0, stream>>>(x1, ln2g, ln2b, h);
  gemm_ffn1<<<dim3(16, 16), 512, 131072, stream>>>(h, W1T, b1, act, 4096, 1024);
  gemm_ffn2<<<dim3(4, 16, 4), 512, 131072, stream>>>(act, W2T,
      (unsigned short*)qb, (unsigned short*)kb, (unsigned short*)vt, (unsigned short*)h);
  reduce_ffn2<<<4096, 256, 0, stream>>>((const unsigned short*)qb, (const unsigned short*)kb,
                                        (const unsigned short*)vt, (const unsigned short*)h,
                                        x1, b2, (float*)d_out);
}